// Round 13
// baseline (4328.687 us; speedup 1.0000x reference)
//
#include <hip/hip_runtime.h>
#include <math.h>
#include <stdint.h>

typedef float f32x4 __attribute__((ext_vector_type(4)));

__device__ __forceinline__ float sigm(float x) { return 1.0f/(1.0f+expf(-x)); }

// sum across the 16-lane DPP row via row_ror rotations (pure VALU, no LDS)
__device__ __forceinline__ float red16(float v) {
    int t;
    t = __builtin_amdgcn_update_dpp(0, __float_as_int(v), 0x128, 0xf, 0xf, false);
    v += __int_as_float(t);   // ror 8
    t = __builtin_amdgcn_update_dpp(0, __float_as_int(v), 0x124, 0xf, 0xf, false);
    v += __int_as_float(t);   // ror 4
    t = __builtin_amdgcn_update_dpp(0, __float_as_int(v), 0x122, 0xf, 0xf, false);
    v += __int_as_float(t);   // ror 2
    t = __builtin_amdgcn_update_dpp(0, __float_as_int(v), 0x121, 0xf, 0xf, false);
    v += __int_as_float(t);   // ror 1
    return v;
}

// async 16B/lane global->LDS (lds dst = wave base + lane*16; global src per-lane)
#define GLD16(g, l) __builtin_amdgcn_global_load_lds( \
    (const __attribute__((address_space(1))) uint32_t*)(g), \
    (__attribute__((address_space(3))) uint32_t*)(l), 16, 0, 0)

// ---------------- Kernel 1: LSTM recurrence, split W stream ----------------
// Round-12 structure (PASSED 4.21ms) with the pipeline-depth fix: BOTH W
// streams (DMA->LDS chunks 0,1; direct->reg chunks 2,3) now have 4-phase
// lookahead. Round-12 flaw: in-order vmcnt queue + 2-deep direct stream meant
// waiting for LOADD(p) forced retirement of phases p+1,p+2 DMA prefetches ->
// effective depth 2 -> ~800 cyc/phase exposed L2 latency.
// Ring: 6 slots x 16KB = 96KB (reuse distance 2 iters + lgkmcnt(0) insurance,
// round-11 lesson). Direct: 4 named pairs A..D (+16 VGPR -> ~104 < 128 cap,
// rounds 7-10 lesson). Per-phase wait vmcnt(14): steady queue = 16 ops
// (4 phases x {2 DMA + 2 direct}); retiring to 14 frees exactly ISSUE(p).
// Direct-load register deps are compiler-managed (auto waitcnt).
// Slot counters are wave-uniform mod-6 (scalar pipe). 2 lgkm barriers/step.
// Reference semantics: cell_state c0 CONSTANT (enc[:,-1,:]); carry = c_new.
__global__ __launch_bounds__(512) void rec_kernel(
    const float* __restrict__ enc,   // (512, 64, 256)
    const float* __restrict__ b_ih,  // (1024)
    const float* __restrict__ W_hh,  // (1024, 256)
    const float* __restrict__ b_hh,  // (1024)
    float* __restrict__ hstage)      // (512, 256, 256) staging (= d_out)
{
    const int tid  = threadIdx.x;
    const int w    = tid >> 6;          // wave 0..7
    const int lane = tid & 63;
    const int kseg = lane & 15;
    const int r2   = lane >> 4;         // 0..3
    const int b0   = blockIdx.x * 4;

    __shared__ float bufWh[6][4096];    // 6 slots x 32 half-rows x 128 = 96KB
    __shared__ float gate_lds[4][1024]; // [batch][gate-row] 16KB
    __shared__ float h_lds[4][256];     // 4KB   (total 116KB)

    // ---- pointwise identity: thread (pj, ph) handles batches 2ph, 2ph+1 ----
    const int pj = tid & 255;
    const int ph = tid >> 8;            // 0..1
    const float c0A = enc[(size_t)(b0 + 2*ph    )*16384 + 16128 + pj];
    const float c0B = enc[(size_t)(b0 + 2*ph + 1)*16384 + 16128 + pj];
    const float pb0 = b_ih[      pj] + b_hh[      pj];
    const float pb1 = b_ih[256 + pj] + b_hh[256 + pj];
    const float pb2 = b_ih[512 + pj] + b_hh[512 + pj];
    const float pb3 = b_ih[768 + pj] + b_hh[768 + pj];
    float* __restrict__ outA = hstage + (size_t)(b0 + 2*ph)*65536 + pj;
    float* __restrict__ outB = outA + 65536;

    const int rloc  = 4*w + r2;         // row-in-phase this lane computes
    const int isrow = lane >> 5;        // DMA: which of 2 half-rows
    const int icol  = (lane & 31) * 4;  // DMA: float offset 0..124

    // DMA chunks 0,1 (floats 0..127) of rows {4w..4w+3} of phase pm:
    #define ISSUE(pm, slot) do {                                               \
        const float* gsrc_ = W_hh + (size_t)((pm)*32 + 4*w + isrow)*256 + icol;\
        GLD16(gsrc_,       &bufWh[slot][(4*w    )*128]);                       \
        GLD16(gsrc_ + 512, &bufWh[slot][(4*w + 2)*128]);                       \
    } while (0)

    // direct-load chunks 2,3 (floats 128..255) of row rloc of phase pm:
    #define LOADD(d0, d1, pm) do {                                             \
        const float* wd_ = W_hh + (size_t)((pm)*32 + rloc)*256 + 128 + kseg*4; \
        d0 = *(const f32x4*)(wd_);                                             \
        d1 = *(const f32x4*)(wd_ + 64);                                        \
    } while (0)

    // chunk order 0,1,2,3 preserved -> bit-identical numerics to rounds 6/12
    #define COMPUTE(d0, d1, slotIdx, p) do {                                   \
        const float* wb_ = &bufWh[0][0] + (slotIdx)*4096 + rloc*128 + kseg*4;  \
        const f32x4 w0_ = *(const f32x4*)(wb_);                                \
        const f32x4 w1_ = *(const f32x4*)(wb_ + 64);                           \
        f32x4 s0 = w0_*h[0][0], s1 = w0_*h[1][0];                              \
        f32x4 s2 = w0_*h[2][0], s3 = w0_*h[3][0];                              \
        s0 += w1_*h[0][1]; s1 += w1_*h[1][1];                                  \
        s2 += w1_*h[2][1]; s3 += w1_*h[3][1];                                  \
        s0 += d0*h[0][2];  s1 += d0*h[1][2];                                   \
        s2 += d0*h[2][2];  s3 += d0*h[3][2];                                   \
        s0 += d1*h[0][3];  s1 += d1*h[1][3];                                   \
        s2 += d1*h[2][3];  s3 += d1*h[3][3];                                   \
        float a0 = (s0.x + s0.y) + (s0.z + s0.w);                              \
        float a1 = (s1.x + s1.y) + (s1.z + s1.w);                              \
        float a2 = (s2.x + s2.y) + (s2.z + s2.w);                              \
        float a3 = (s3.x + s3.y) + (s3.z + s3.w);                              \
        a0 = red16(a0); a1 = red16(a1); a2 = red16(a2); a3 = red16(a3);        \
        if (kseg == 0) {                                                       \
            const int grow_ = (p)*32 + rloc;                                   \
            gate_lds[0][grow_] = a0;                                           \
            gate_lds[1][grow_] = a1;                                           \
            gate_lds[2][grow_] = a2;                                           \
            gate_lds[3][grow_] = a3;                                           \
        }                                                                      \
    } while (0)

    #define PHASE(d0, d1, p) do {                                              \
        asm volatile("s_waitcnt vmcnt(14) lgkmcnt(0)" ::: "memory");           \
        ISSUE(((p) + 4) & 31, sIss); sIss = (sIss == 5) ? 0 : sIss + 1;        \
        COMPUTE(d0, d1, sRd, (p));   sRd  = (sRd  == 5) ? 0 : sRd  + 1;        \
        LOADD(d0, d1, ((p) + 4) & 31);                                         \
    } while (0)

    // h windows in registers: h[batch][i] = h[b][(i*16+kseg)*4 ..+3]
    f32x4 h[4][4];
    #pragma unroll
    for (int b = 0; b < 4; ++b)
        #pragma unroll
        for (int i = 0; i < 4; ++i) h[b][i] = (f32x4)(0.0f);

    f32x4 wA0, wA1, wB0, wB1, wC0, wC1, wD0, wD1;   // 4-deep direct pipeline

    // prologue: prime both streams with phases 0..3 (16 vm ops in flight)
    ISSUE(0, 0); LOADD(wA0, wA1, 0);
    ISSUE(1, 1); LOADD(wB0, wB1, 1);
    ISSUE(2, 2); LOADD(wC0, wC1, 2);
    ISSUE(3, 3); LOADD(wD0, wD1, 3);
    int sIss = 4;   // slot of next ISSUE  (ISSUE #n -> slot n mod 6)
    int sRd  = 0;   // slot of next COMPUTE (COMPUTE #m -> slot m mod 6)

    for (int t = 0; t < 256; ++t) {
        #pragma unroll 1
        for (int pq = 0; pq < 8; ++pq) {
            const int p = pq*4;
            PHASE(wA0, wA1, p    );     // p+4..p+7 wrap (&31) to next step's
            PHASE(wB0, wB1, p + 1);     // phases 0..3: W identical every step,
            PHASE(wC0, wC1, p + 2);     // counters persist -> invariant holds
            PHASE(wD0, wD1, p + 3);
        }
        asm volatile("s_waitcnt lgkmcnt(0)" ::: "memory");
        __builtin_amdgcn_s_barrier();           // (1) all gates visible

        // ---- pointwise LSTM for batches 2ph, 2ph+1, column pj ----
        {
            const float gA0 = gate_lds[2*ph    ][      pj] + pb0;
            const float gA1 = gate_lds[2*ph    ][256 + pj] + pb1;
            const float gA2 = gate_lds[2*ph    ][512 + pj] + pb2;
            const float gA3 = gate_lds[2*ph    ][768 + pj] + pb3;
            const float gB0 = gate_lds[2*ph + 1][      pj] + pb0;
            const float gB1 = gate_lds[2*ph + 1][256 + pj] + pb1;
            const float gB2 = gate_lds[2*ph + 1][512 + pj] + pb2;
            const float gB3 = gate_lds[2*ph + 1][768 + pj] + pb3;
            const float cnA = sigm(gA1)*c0A + sigm(gA0)*tanhf(gA2);
            const float cnB = sigm(gB1)*c0B + sigm(gB0)*tanhf(gB2);
            const float hnA = sigm(gA3)*tanhf(cnA);
            const float hnB = sigm(gB3)*tanhf(cnB);
            h_lds[2*ph    ][pj] = cnA;          // carry h_{t+1} = c_new
            h_lds[2*ph + 1][pj] = cnB;
            __builtin_nontemporal_store(hnA, outA + t*256);
            __builtin_nontemporal_store(hnB, outB + t*256);
        }
        asm volatile("s_waitcnt lgkmcnt(0)" ::: "memory");
        __builtin_amdgcn_s_barrier();           // (2) h ready

        // reload h windows (2-way bank aliasing = free)
        #pragma unroll
        for (int b = 0; b < 4; ++b)
            #pragma unroll
            for (int i = 0; i < 4; ++i)
                h[b][i] = *(const f32x4*)&h_lds[b][(i*16 + kseg)*4];
    }
    asm volatile("s_waitcnt vmcnt(0)" ::: "memory");  // drain DMA before endpgm
    #undef PHASE
    #undef ISSUE
    #undef LOADD
    #undef COMPUTE
}

// ---------------- Kernel 2: logits + softmax, in place ----------------
// (unchanged — verified correct, ~106 us measured from dispatch gap)
__global__ __launch_bounds__(1024) void out_kernel(
    const float* __restrict__ W2,    // (256, 256)
    const float* __restrict__ b2,    // (256)
    float* __restrict__ io)          // (131072, 256) h in, probs out
{
    const int tid = threadIdx.x;
    const int rg  = tid & 15;
    const int cg  = tid >> 4;        // 0..63
    const int m0  = blockIdx.x * 64;

    __shared__ float tile[64][260];

    #pragma unroll
    for (int i = 0; i < 4; ++i) {
        const int idx = tid + i*1024;     // 0..4095 float4 slots
        const int r   = idx >> 6;
        const int c4  = idx & 63;
        const f32x4 v = __builtin_nontemporal_load(
            (const f32x4*)(io + (size_t)(m0 + r)*256 + c4*4));
        *(f32x4*)&tile[r][c4*4] = v;
    }
    __syncthreads();

    float b2v[4];
    #pragma unroll
    for (int ci = 0; ci < 4; ++ci) b2v[ci] = b2[cg*4 + ci];

    float acc[4][4] = {};

    #pragma unroll 4
    for (int k4 = 0; k4 < 64; ++k4) {
        const f32x4 h0 = *(const f32x4*)&tile[rg     ][k4*4];
        const f32x4 h1 = *(const f32x4*)&tile[rg + 16][k4*4];
        const f32x4 h2 = *(const f32x4*)&tile[rg + 32][k4*4];
        const f32x4 h3 = *(const f32x4*)&tile[rg + 48][k4*4];
        #pragma unroll
        for (int ci = 0; ci < 4; ++ci) {
            const f32x4 wv = *(const f32x4*)(W2 + (size_t)(cg*4 + ci)*256 + k4*4);
            acc[0][ci] += wv.x*h0.x + wv.y*h0.y + wv.z*h0.z + wv.w*h0.w;
            acc[1][ci] += wv.x*h1.x + wv.y*h1.y + wv.z*h1.z + wv.w*h1.w;
            acc[2][ci] += wv.x*h2.x + wv.y*h2.y + wv.z*h2.z + wv.w*h2.w;
            acc[3][ci] += wv.x*h3.x + wv.y*h3.y + wv.z*h3.z + wv.w*h3.w;
        }
    }
    __syncthreads();

    #pragma unroll
    for (int ri = 0; ri < 4; ++ri) {
        f32x4 v;
        v.x = acc[ri][0] + b2v[0];
        v.y = acc[ri][1] + b2v[1];
        v.z = acc[ri][2] + b2v[2];
        v.w = acc[ri][3] + b2v[3];
        *(f32x4*)&tile[rg + 16*ri][cg*4] = v;
    }
    __syncthreads();

    const int wv_ = tid >> 6;
    const int l   = tid & 63;
    #pragma unroll
    for (int rr2 = 0; rr2 < 4; ++rr2) {
        const int r = wv_*4 + rr2;
        const float v0 = tile[r][l      ];
        const float v1 = tile[r][l +  64];
        const float v2 = tile[r][l + 128];
        const float v3 = tile[r][l + 192];
        float m = fmaxf(fmaxf(v0, v1), fmaxf(v2, v3));
        #pragma unroll
        for (int off = 32; off > 0; off >>= 1)
            m = fmaxf(m, __shfl_xor(m, off));
        const float e0 = expf(v0 - m), e1 = expf(v1 - m);
        const float e2 = expf(v2 - m), e3 = expf(v3 - m);
        float s = e0 + e1 + e2 + e3;
        #pragma unroll
        for (int off = 32; off > 0; off >>= 1)
            s += __shfl_xor(s, off);
        const float inv = 1.0f / s;
        float* op = io + (size_t)(m0 + r)*256;
        __builtin_nontemporal_store(e0*inv, op + l      );
        __builtin_nontemporal_store(e1*inv, op + l +  64);
        __builtin_nontemporal_store(e2*inv, op + l + 128);
        __builtin_nontemporal_store(e3*inv, op + l + 192);
    }
}

extern "C" void kernel_launch(void* const* d_in, const int* in_sizes, int n_in,
                              void* d_out, int out_size, void* d_ws, size_t ws_size,
                              hipStream_t stream) {
    // inputs: input, encoder_output, W_ih, b_ih, W_hh, b_hh, W2, b2
    // (input and W_ih are mathematically unused: x_part = 0 @ W_ih.T + b_ih)
    const float* enc  = (const float*)d_in[1];
    const float* b_ih = (const float*)d_in[3];
    const float* W_hh = (const float*)d_in[4];
    const float* b_hh = (const float*)d_in[5];
    const float* W2   = (const float*)d_in[6];
    const float* b2   = (const float*)d_in[7];
    float* outp = (float*)d_out;

    hipLaunchKernelGGL(rec_kernel, dim3(128), dim3(512), 0, stream,
                       enc, b_ih, W_hh, b_hh, outp);
    hipLaunchKernelGGL(out_kernel, dim3(2048), dim3(1024), 0, stream,
                       W2, b2, outp);
}

// Round 14
// 3305.805 us; speedup vs baseline: 1.3094x; 1.3094x over previous
//
#include <hip/hip_runtime.h>
#include <math.h>
#include <stdint.h>

typedef float f32x4 __attribute__((ext_vector_type(4)));

__device__ __forceinline__ float sigm(float x) { return 1.0f/(1.0f+expf(-x)); }

// sum across the 16-lane DPP row via row_ror rotations (pure VALU, no LDS)
__device__ __forceinline__ float red16(float v) {
    int t;
    t = __builtin_amdgcn_update_dpp(0, __float_as_int(v), 0x128, 0xf, 0xf, false);
    v += __int_as_float(t);   // ror 8
    t = __builtin_amdgcn_update_dpp(0, __float_as_int(v), 0x124, 0xf, 0xf, false);
    v += __int_as_float(t);   // ror 4
    t = __builtin_amdgcn_update_dpp(0, __float_as_int(v), 0x122, 0xf, 0xf, false);
    v += __int_as_float(t);   // ror 2
    t = __builtin_amdgcn_update_dpp(0, __float_as_int(v), 0x121, 0xf, 0xf, false);
    v += __int_as_float(t);   // ror 1
    return v;
}

// async 16B/lane global->LDS (lds dst = wave base + lane*16; global src per-lane)
#define GLD16(g, l) __builtin_amdgcn_global_load_lds( \
    (const __attribute__((address_space(1))) uint32_t*)(g), \
    (__attribute__((address_space(3))) uint32_t*)(l), 16, 0, 0)

// ---------------- Kernel 1: LSTM recurrence, split W stream ----------------
// Round-13 phase machinery (PASSED, 4.23ms) scaled to ALL 256 CUs:
// 256 blocks x 512 threads, 2 batch rows/block. Round-13 diagnosis: with 128
// blocks half the chip idled and active CUs were ~62% VALU-busy; chip-wide
// W-re-stream roofline = 256CU x 256step x 1MiB / 34.5TB/s L2 ~ 1.85ms, and
// per-CU L1 (64B/cyc) gives the same ~6.8us/step. Halving rows/block halves
// per-CU VALU (~3.4us/step < BW floor) -> cleanly BW-bound on a full chip.
// W streams: chunks 0,1 DMA->LDS 6-slot ring (96KB); chunks 2,3 direct->reg
// (4 named pairs). Both streams 4-phase lookahead; per-phase wait
// vmcnt(14) (steady queue 16 = 4 phases x {2 DMA + 2 direct}; retiring to 14
// frees exactly ISSUE(p)) + lgkmcnt(0) (round-11 lesson: never DMA into a
// slot whose prior ds_reads aren't lgkm-retired; free here). Slot counters
// wave-uniform mod-6. 2 lgkm barriers/step. Math per batch row bit-identical
// to rounds 6/12/13. Reference semantics: cell_state c0 CONSTANT
// (enc[:,-1,:]); scan carry h_{t+1} = c_new_t.
__global__ __launch_bounds__(512) void rec_kernel(
    const float* __restrict__ enc,   // (512, 64, 256)
    const float* __restrict__ b_ih,  // (1024)
    const float* __restrict__ W_hh,  // (1024, 256)
    const float* __restrict__ b_hh,  // (1024)
    float* __restrict__ hstage)      // (512, 256, 256) staging (= d_out)
{
    const int tid  = threadIdx.x;
    const int w    = tid >> 6;          // wave 0..7
    const int lane = tid & 63;
    const int kseg = lane & 15;
    const int r2   = lane >> 4;         // 0..3
    const int b0   = blockIdx.x * 2;

    __shared__ float bufWh[6][4096];    // 6 slots x 32 half-rows x 128 = 96KB
    __shared__ float gate_lds[2][1024]; // [batch][gate-row] 8KB
    __shared__ float h_lds[2][256];     // 2KB   (total 106KB)

    // ---- pointwise identity: thread (pj, ph) handles batch b0+ph ----
    const int pj = tid & 255;
    const int ph = tid >> 8;            // 0..1
    const float c0  = enc[(size_t)(b0 + ph)*16384 + 16128 + pj];
    const float pb0 = b_ih[      pj] + b_hh[      pj];
    const float pb1 = b_ih[256 + pj] + b_hh[256 + pj];
    const float pb2 = b_ih[512 + pj] + b_hh[512 + pj];
    const float pb3 = b_ih[768 + pj] + b_hh[768 + pj];
    float* __restrict__ outp = hstage + (size_t)(b0 + ph)*65536 + pj;

    const int rloc  = 4*w + r2;         // row-in-phase this lane computes
    const int isrow = lane >> 5;        // DMA: which of 2 half-rows
    const int icol  = (lane & 31) * 4;  // DMA: float offset 0..124

    // DMA chunks 0,1 (floats 0..127) of rows {4w..4w+3} of phase pm:
    #define ISSUE(pm, slot) do {                                               \
        const float* gsrc_ = W_hh + (size_t)((pm)*32 + 4*w + isrow)*256 + icol;\
        GLD16(gsrc_,       &bufWh[slot][(4*w    )*128]);                       \
        GLD16(gsrc_ + 512, &bufWh[slot][(4*w + 2)*128]);                       \
    } while (0)

    // direct-load chunks 2,3 (floats 128..255) of row rloc of phase pm:
    #define LOADD(d0, d1, pm) do {                                             \
        const float* wd_ = W_hh + (size_t)((pm)*32 + rloc)*256 + 128 + kseg*4; \
        d0 = *(const f32x4*)(wd_);                                             \
        d1 = *(const f32x4*)(wd_ + 64);                                        \
    } while (0)

    // chunk order 0,1,2,3 preserved -> bit-identical numerics per batch row
    #define COMPUTE(d0, d1, slotIdx, p) do {                                   \
        const float* wb_ = &bufWh[0][0] + (slotIdx)*4096 + rloc*128 + kseg*4;  \
        const f32x4 w0_ = *(const f32x4*)(wb_);                                \
        const f32x4 w1_ = *(const f32x4*)(wb_ + 64);                           \
        f32x4 s0 = w0_*h[0][0], s1 = w0_*h[1][0];                              \
        s0 += w1_*h[0][1]; s1 += w1_*h[1][1];                                  \
        s0 += d0*h[0][2];  s1 += d0*h[1][2];                                   \
        s0 += d1*h[0][3];  s1 += d1*h[1][3];                                   \
        float a0 = (s0.x + s0.y) + (s0.z + s0.w);                              \
        float a1 = (s1.x + s1.y) + (s1.z + s1.w);                              \
        a0 = red16(a0); a1 = red16(a1);                                        \
        if (kseg == 0) {                                                       \
            const int grow_ = (p)*32 + rloc;                                   \
            gate_lds[0][grow_] = a0;                                           \
            gate_lds[1][grow_] = a1;                                           \
        }                                                                      \
    } while (0)

    #define PHASE(d0, d1, p) do {                                              \
        asm volatile("s_waitcnt vmcnt(14) lgkmcnt(0)" ::: "memory");           \
        ISSUE(((p) + 4) & 31, sIss); sIss = (sIss == 5) ? 0 : sIss + 1;        \
        COMPUTE(d0, d1, sRd, (p));   sRd  = (sRd  == 5) ? 0 : sRd  + 1;        \
        LOADD(d0, d1, ((p) + 4) & 31);                                         \
    } while (0)

    // h windows in registers: h[batch][i] = h[b][(i*16+kseg)*4 ..+3]
    f32x4 h[2][4];
    #pragma unroll
    for (int b = 0; b < 2; ++b)
        #pragma unroll
        for (int i = 0; i < 4; ++i) h[b][i] = (f32x4)(0.0f);

    f32x4 wA0, wA1, wB0, wB1, wC0, wC1, wD0, wD1;   // 4-deep direct pipeline

    // prologue: prime both streams with phases 0..3 (16 vm ops in flight)
    ISSUE(0, 0); LOADD(wA0, wA1, 0);
    ISSUE(1, 1); LOADD(wB0, wB1, 1);
    ISSUE(2, 2); LOADD(wC0, wC1, 2);
    ISSUE(3, 3); LOADD(wD0, wD1, 3);
    int sIss = 4;   // slot of next ISSUE  (ISSUE #n -> slot n mod 6)
    int sRd  = 0;   // slot of next COMPUTE (COMPUTE #m -> slot m mod 6)

    for (int t = 0; t < 256; ++t) {
        #pragma unroll 1
        for (int pq = 0; pq < 8; ++pq) {
            const int p = pq*4;
            PHASE(wA0, wA1, p    );     // p+4..p+7 wrap (&31) to next step's
            PHASE(wB0, wB1, p + 1);     // phases 0..3: W identical every step,
            PHASE(wC0, wC1, p + 2);     // counters persist -> invariant holds
            PHASE(wD0, wD1, p + 3);
        }
        asm volatile("s_waitcnt lgkmcnt(0)" ::: "memory");
        __builtin_amdgcn_s_barrier();           // (1) all gates visible

        // ---- pointwise LSTM for batch b0+ph, column pj ----
        {
            const float g0 = gate_lds[ph][      pj] + pb0;
            const float g1 = gate_lds[ph][256 + pj] + pb1;
            const float g2 = gate_lds[ph][512 + pj] + pb2;
            const float g3 = gate_lds[ph][768 + pj] + pb3;
            const float cn = sigm(g1)*c0 + sigm(g0)*tanhf(g2);
            const float hn = sigm(g3)*tanhf(cn);
            h_lds[ph][pj] = cn;                 // carry h_{t+1} = c_new
            __builtin_nontemporal_store(hn, outp + t*256);
        }
        asm volatile("s_waitcnt lgkmcnt(0)" ::: "memory");
        __builtin_amdgcn_s_barrier();           // (2) h ready

        // reload h windows (2-way bank aliasing = free)
        #pragma unroll
        for (int b = 0; b < 2; ++b)
            #pragma unroll
            for (int i = 0; i < 4; ++i)
                h[b][i] = *(const f32x4*)&h_lds[b][(i*16 + kseg)*4];
    }
    asm volatile("s_waitcnt vmcnt(0)" ::: "memory");  // drain DMA before endpgm
    #undef PHASE
    #undef ISSUE
    #undef LOADD
    #undef COMPUTE
}

// ---------------- Kernel 2: logits + softmax, in place ----------------
// (unchanged — verified correct, ~106 us measured from dispatch gap)
__global__ __launch_bounds__(1024) void out_kernel(
    const float* __restrict__ W2,    // (256, 256)
    const float* __restrict__ b2,    // (256)
    float* __restrict__ io)          // (131072, 256) h in, probs out
{
    const int tid = threadIdx.x;
    const int rg  = tid & 15;
    const int cg  = tid >> 4;        // 0..63
    const int m0  = blockIdx.x * 64;

    __shared__ float tile[64][260];

    #pragma unroll
    for (int i = 0; i < 4; ++i) {
        const int idx = tid + i*1024;     // 0..4095 float4 slots
        const int r   = idx >> 6;
        const int c4  = idx & 63;
        const f32x4 v = __builtin_nontemporal_load(
            (const f32x4*)(io + (size_t)(m0 + r)*256 + c4*4));
        *(f32x4*)&tile[r][c4*4] = v;
    }
    __syncthreads();

    float b2v[4];
    #pragma unroll
    for (int ci = 0; ci < 4; ++ci) b2v[ci] = b2[cg*4 + ci];

    float acc[4][4] = {};

    #pragma unroll 4
    for (int k4 = 0; k4 < 64; ++k4) {
        const f32x4 h0 = *(const f32x4*)&tile[rg     ][k4*4];
        const f32x4 h1 = *(const f32x4*)&tile[rg + 16][k4*4];
        const f32x4 h2 = *(const f32x4*)&tile[rg + 32][k4*4];
        const f32x4 h3 = *(const f32x4*)&tile[rg + 48][k4*4];
        #pragma unroll
        for (int ci = 0; ci < 4; ++ci) {
            const f32x4 wv = *(const f32x4*)(W2 + (size_t)(cg*4 + ci)*256 + k4*4);
            acc[0][ci] += wv.x*h0.x + wv.y*h0.y + wv.z*h0.z + wv.w*h0.w;
            acc[1][ci] += wv.x*h1.x + wv.y*h1.y + wv.z*h1.z + wv.w*h1.w;
            acc[2][ci] += wv.x*h2.x + wv.y*h2.y + wv.z*h2.z + wv.w*h2.w;
            acc[3][ci] += wv.x*h3.x + wv.y*h3.y + wv.z*h3.z + wv.w*h3.w;
        }
    }
    __syncthreads();

    #pragma unroll
    for (int ri = 0; ri < 4; ++ri) {
        f32x4 v;
        v.x = acc[ri][0] + b2v[0];
        v.y = acc[ri][1] + b2v[1];
        v.z = acc[ri][2] + b2v[2];
        v.w = acc[ri][3] + b2v[3];
        *(f32x4*)&tile[rg + 16*ri][cg*4] = v;
    }
    __syncthreads();

    const int wv_ = tid >> 6;
    const int l   = tid & 63;
    #pragma unroll
    for (int rr2 = 0; rr2 < 4; ++rr2) {
        const int r = wv_*4 + rr2;
        const float v0 = tile[r][l      ];
        const float v1 = tile[r][l +  64];
        const float v2 = tile[r][l + 128];
        const float v3 = tile[r][l + 192];
        float m = fmaxf(fmaxf(v0, v1), fmaxf(v2, v3));
        #pragma unroll
        for (int off = 32; off > 0; off >>= 1)
            m = fmaxf(m, __shfl_xor(m, off));
        const float e0 = expf(v0 - m), e1 = expf(v1 - m);
        const float e2 = expf(v2 - m), e3 = expf(v3 - m);
        float s = e0 + e1 + e2 + e3;
        #pragma unroll
        for (int off = 32; off > 0; off >>= 1)
            s += __shfl_xor(s, off);
        const float inv = 1.0f / s;
        float* op = io + (size_t)(m0 + r)*256;
        __builtin_nontemporal_store(e0*inv, op + l      );
        __builtin_nontemporal_store(e1*inv, op + l +  64);
        __builtin_nontemporal_store(e2*inv, op + l + 128);
        __builtin_nontemporal_store(e3*inv, op + l + 192);
    }
}

extern "C" void kernel_launch(void* const* d_in, const int* in_sizes, int n_in,
                              void* d_out, int out_size, void* d_ws, size_t ws_size,
                              hipStream_t stream) {
    // inputs: input, encoder_output, W_ih, b_ih, W_hh, b_hh, W2, b2
    // (input and W_ih are mathematically unused: x_part = 0 @ W_ih.T + b_ih)
    const float* enc  = (const float*)d_in[1];
    const float* b_ih = (const float*)d_in[3];
    const float* W_hh = (const float*)d_in[4];
    const float* b_hh = (const float*)d_in[5];
    const float* W2   = (const float*)d_in[6];
    const float* b2   = (const float*)d_in[7];
    float* outp = (float*)d_out;

    hipLaunchKernelGGL(rec_kernel, dim3(256), dim3(512), 0, stream,
                       enc, b_ih, W_hh, b_hh, outp);
    hipLaunchKernelGGL(out_kernel, dim3(2048), dim3(1024), 0, stream,
                       W2, b2, outp);
}

// Round 15
// 2666.144 us; speedup vs baseline: 1.6236x; 1.2399x over previous
//
#include <hip/hip_runtime.h>
#include <math.h>
#include <stdint.h>

typedef float f32x4 __attribute__((ext_vector_type(4)));

__device__ __forceinline__ float sigm(float x) { return 1.0f/(1.0f+expf(-x)); }

// sum across the 16-lane DPP row via row_ror rotations (pure VALU, no LDS)
__device__ __forceinline__ float red16(float v) {
    int t;
    t = __builtin_amdgcn_update_dpp(0, __float_as_int(v), 0x128, 0xf, 0xf, false);
    v += __int_as_float(t);   // ror 8
    t = __builtin_amdgcn_update_dpp(0, __float_as_int(v), 0x124, 0xf, 0xf, false);
    v += __int_as_float(t);   // ror 4
    t = __builtin_amdgcn_update_dpp(0, __float_as_int(v), 0x122, 0xf, 0xf, false);
    v += __int_as_float(t);   // ror 2
    t = __builtin_amdgcn_update_dpp(0, __float_as_int(v), 0x121, 0xf, 0xf, false);
    v += __int_as_float(t);   // ror 1
    return v;
}

// ------------- Kernel 1: LSTM recurrence, all-direct K-split waves -------------
// Round-14 diagnosis: at 2 waves/SIMD, VALU (6.5us) and W-stream (6.8us) were
// ADDITIVE (13.7us/step) -- both waves stall in the same vmcnt window. Fix:
// 1024 threads/block (16 waves, 4/SIMD, 256 blocks, 2 batch rows each) and
// split the K dimension across wave halves: wave w<8 streams W chunks {0,1},
// w>=8 chunks {2,3}, ALL direct-to-register (2 f32x4/phase x 4-deep named
// pairs = 32 VGPR; no LDS DMA ring, no asm vmcnt, no round-11 race class --
// compiler emits counted vmcnt on register deps automatically). Per-wave
// half-sums are combined via part[2][2][1024] in LDS; pointwise adds halves.
// W_hh stays L2/L1-resident (FETCH ~4.4MB measured). VGPR budget ~85 < 128
// (the hard cap rounds 7-10 established; 1024 threads demand <=128 anyway).
// 2 lgkm-only barriers/step. Reference semantics: cell_state c0 CONSTANT
// (enc[:,-1,:]); scan carry h_{t+1} = c_new_t.
__global__ __launch_bounds__(1024) void rec_kernel(
    const float* __restrict__ enc,   // (512, 64, 256)
    const float* __restrict__ b_ih,  // (1024)
    const float* __restrict__ W_hh,  // (1024, 256)
    const float* __restrict__ b_hh,  // (1024)
    float* __restrict__ hstage)      // (512, 256, 256) staging (= d_out)
{
    const int tid  = threadIdx.x;
    const int wv   = tid >> 6;          // wave 0..15
    const int lane = tid & 63;
    const int kseg = lane & 15;
    const int r2   = lane >> 4;         // 0..3
    const int half = wv >> 3;           // K-half: 0 -> chunks 0,1; 1 -> 2,3
    const int wg   = wv & 7;            // row group
    const int rloc = 4*wg + r2;         // row-in-phase this lane computes
    const int b0   = blockIdx.x * 2;

    __shared__ float part[2][2][1024];  // [half][batch][gate-row] 16KB
    __shared__ float h_lds[2][256];     // 2KB

    // ---- pointwise identity: threads 0..511 = (pj, ph) ----
    const int pj = tid & 255;
    const int ph = (tid >> 8) & 1;
    float c0 = 0.f, pb0 = 0.f, pb1 = 0.f, pb2 = 0.f, pb3 = 0.f;
    float* __restrict__ outp = nullptr;
    if (tid < 512) {
        c0  = enc[(size_t)(b0 + ph)*16384 + 16128 + pj];
        pb0 = b_ih[      pj] + b_hh[      pj];
        pb1 = b_ih[256 + pj] + b_hh[256 + pj];
        pb2 = b_ih[512 + pj] + b_hh[512 + pj];
        pb3 = b_ih[768 + pj] + b_hh[768 + pj];
        outp = hstage + (size_t)(b0 + ph)*65536 + pj;
    }

    // per-lane W base: phase pm, this wave's half; two f32x4 at +0, +64
    const float* __restrict__ wbase =
        W_hh + (size_t)rloc*256 + half*128 + kseg*4;

    #define LOADD(d0, d1, pm) do {                                   \
        const float* wp_ = wbase + (size_t)(pm)*8192;                \
        d0 = *(const f32x4*)(wp_);                                   \
        d1 = *(const f32x4*)(wp_ + 64);                              \
    } while (0)

    #define COMPUTE(d0, d1, p) do {                                  \
        f32x4 s0 = d0*h0A; s0 += d1*h0B;                             \
        f32x4 s1 = d0*h1A; s1 += d1*h1B;                             \
        float a0 = (s0.x + s0.y) + (s0.z + s0.w);                    \
        float a1 = (s1.x + s1.y) + (s1.z + s1.w);                    \
        a0 = red16(a0); a1 = red16(a1);                              \
        if (kseg == 0) {                                             \
            const int grow_ = (p)*32 + rloc;                         \
            part[half][0][grow_] = a0;                               \
            part[half][1][grow_] = a1;                               \
        }                                                            \
    } while (0)

    // h windows (this wave's 2 K-chunks x 2 batch rows = 16 VGPR)
    f32x4 h0A = (f32x4)(0.f), h0B = (f32x4)(0.f);
    f32x4 h1A = (f32x4)(0.f), h1B = (f32x4)(0.f);

    f32x4 wA0, wA1, wB0, wB1, wC0, wC1, wD0, wD1;   // 4-deep pipeline

    // prologue: prime phases 0..3 (8 loads/wave in flight)
    LOADD(wA0, wA1, 0); LOADD(wB0, wB1, 1);
    LOADD(wC0, wC1, 2); LOADD(wD0, wD1, 3);

    for (int t = 0; t < 256; ++t) {
        #pragma unroll 1
        for (int pq = 0; pq < 8; ++pq) {
            const int p = pq*4;
            COMPUTE(wA0, wA1, p    ); LOADD(wA0, wA1, (p + 4) & 31);
            COMPUTE(wB0, wB1, p + 1); LOADD(wB0, wB1, (p + 5) & 31);
            COMPUTE(wC0, wC1, p + 2); LOADD(wC0, wC1, (p + 6) & 31);
            COMPUTE(wD0, wD1, p + 3); LOADD(wD0, wD1, (p + 7) & 31);
        }   // (p+4..p+7 wrap to next step's phases: W identical every step)
        asm volatile("s_waitcnt lgkmcnt(0)" ::: "memory");
        __builtin_amdgcn_s_barrier();           // (1) all partials visible

        // ---- pointwise LSTM: threads 0..511, batch b0+ph, column pj ----
        if (tid < 512) {
            const float g0 = part[0][ph][      pj] + part[1][ph][      pj] + pb0;
            const float g1 = part[0][ph][256 + pj] + part[1][ph][256 + pj] + pb1;
            const float g2 = part[0][ph][512 + pj] + part[1][ph][512 + pj] + pb2;
            const float g3 = part[0][ph][768 + pj] + part[1][ph][768 + pj] + pb3;
            const float cn = sigm(g1)*c0 + sigm(g0)*tanhf(g2);
            const float hn = sigm(g3)*tanhf(cn);
            h_lds[ph][pj] = cn;                 // carry h_{t+1} = c_new
            __builtin_nontemporal_store(hn, outp + t*256);
        }
        asm volatile("s_waitcnt lgkmcnt(0)" ::: "memory");
        __builtin_amdgcn_s_barrier();           // (2) h ready

        // reload this wave's h window (broadcast across r2 lanes = free)
        h0A = *(const f32x4*)&h_lds[0][half*128 +      kseg*4];
        h0B = *(const f32x4*)&h_lds[0][half*128 + 64 + kseg*4];
        h1A = *(const f32x4*)&h_lds[1][half*128 +      kseg*4];
        h1B = *(const f32x4*)&h_lds[1][half*128 + 64 + kseg*4];
    }
    #undef LOADD
    #undef COMPUTE
}

// ---------------- Kernel 2: logits + softmax, in place ----------------
// (unchanged — verified correct, ~106 us)
__global__ __launch_bounds__(1024) void out_kernel(
    const float* __restrict__ W2,    // (256, 256)
    const float* __restrict__ b2,    // (256)
    float* __restrict__ io)          // (131072, 256) h in, probs out
{
    const int tid = threadIdx.x;
    const int rg  = tid & 15;
    const int cg  = tid >> 4;        // 0..63
    const int m0  = blockIdx.x * 64;

    __shared__ float tile[64][260];

    #pragma unroll
    for (int i = 0; i < 4; ++i) {
        const int idx = tid + i*1024;     // 0..4095 float4 slots
        const int r   = idx >> 6;
        const int c4  = idx & 63;
        const f32x4 v = __builtin_nontemporal_load(
            (const f32x4*)(io + (size_t)(m0 + r)*256 + c4*4));
        *(f32x4*)&tile[r][c4*4] = v;
    }
    __syncthreads();

    float b2v[4];
    #pragma unroll
    for (int ci = 0; ci < 4; ++ci) b2v[ci] = b2[cg*4 + ci];

    float acc[4][4] = {};

    #pragma unroll 4
    for (int k4 = 0; k4 < 64; ++k4) {
        const f32x4 h0 = *(const f32x4*)&tile[rg     ][k4*4];
        const f32x4 h1 = *(const f32x4*)&tile[rg + 16][k4*4];
        const f32x4 h2 = *(const f32x4*)&tile[rg + 32][k4*4];
        const f32x4 h3 = *(const f32x4*)&tile[rg + 48][k4*4];
        #pragma unroll
        for (int ci = 0; ci < 4; ++ci) {
            const f32x4 wv = *(const f32x4*)(W2 + (size_t)(cg*4 + ci)*256 + k4*4);
            acc[0][ci] += wv.x*h0.x + wv.y*h0.y + wv.z*h0.z + wv.w*h0.w;
            acc[1][ci] += wv.x*h1.x + wv.y*h1.y + wv.z*h1.z + wv.w*h1.w;
            acc[2][ci] += wv.x*h2.x + wv.y*h2.y + wv.z*h2.z + wv.w*h2.w;
            acc[3][ci] += wv.x*h3.x + wv.y*h3.y + wv.z*h3.z + wv.w*h3.w;
        }
    }
    __syncthreads();

    #pragma unroll
    for (int ri = 0; ri < 4; ++ri) {
        f32x4 v;
        v.x = acc[ri][0] + b2v[0];
        v.y = acc[ri][1] + b2v[1];
        v.z = acc[ri][2] + b2v[2];
        v.w = acc[ri][3] + b2v[3];
        *(f32x4*)&tile[rg + 16*ri][cg*4] = v;
    }
    __syncthreads();

    const int wv_ = tid >> 6;
    const int l   = tid & 63;
    #pragma unroll
    for (int rr2 = 0; rr2 < 4; ++rr2) {
        const int r = wv_*4 + rr2;
        const float v0 = tile[r][l      ];
        const float v1 = tile[r][l +  64];
        const float v2 = tile[r][l + 128];
        const float v3 = tile[r][l + 192];
        float m = fmaxf(fmaxf(v0, v1), fmaxf(v2, v3));
        #pragma unroll
        for (int off = 32; off > 0; off >>= 1)
            m = fmaxf(m, __shfl_xor(m, off));
        const float e0 = expf(v0 - m), e1 = expf(v1 - m);
        const float e2 = expf(v2 - m), e3 = expf(v3 - m);
        float s = e0 + e1 + e2 + e3;
        #pragma unroll
        for (int off = 32; off > 0; off >>= 1)
            s += __shfl_xor(s, off);
        const float inv = 1.0f / s;
        float* op = io + (size_t)(m0 + r)*256;
        __builtin_nontemporal_store(e0*inv, op + l      );
        __builtin_nontemporal_store(e1*inv, op + l +  64);
        __builtin_nontemporal_store(e2*inv, op + l + 128);
        __builtin_nontemporal_store(e3*inv, op + l + 192);
    }
}

extern "C" void kernel_launch(void* const* d_in, const int* in_sizes, int n_in,
                              void* d_out, int out_size, void* d_ws, size_t ws_size,
                              hipStream_t stream) {
    // inputs: input, encoder_output, W_ih, b_ih, W_hh, b_hh, W2, b2
    // (input and W_ih are mathematically unused: x_part = 0 @ W_ih.T + b_ih)
    const float* enc  = (const float*)d_in[1];
    const float* b_ih = (const float*)d_in[3];
    const float* W_hh = (const float*)d_in[4];
    const float* b_hh = (const float*)d_in[5];
    const float* W2   = (const float*)d_in[6];
    const float* b2   = (const float*)d_in[7];
    float* outp = (float*)d_out;

    hipLaunchKernelGGL(rec_kernel, dim3(256), dim3(1024), 0, stream,
                       enc, b_ih, W_hh, b_hh, outp);
    hipLaunchKernelGGL(out_kernel, dim3(2048), dim3(1024), 0, stream,
                       W2, b2, outp);
}